// Round 3
// baseline (1029.457 us; speedup 1.0000x reference)
//
#include <hip/hip_runtime.h>
#include <hip/hip_bf16.h>

#define NA 100000
#define HH 256
#define FF 2048
#define SCAL_BLOCKS 1563            // (NA+63)/64
#define VEC_BLOCKS  25000           // NA/4
#define MEGA_BLOCKS 26563           // 17*1563 = 26571 >= total; we use exact partition below

typedef __attribute__((ext_vector_type(4))) float f32x4;
typedef __attribute__((ext_vector_type(8))) short short8;
typedef __attribute__((ext_vector_type(8))) __bf16 bf16x8;
typedef unsigned short u16;
typedef __attribute__((ext_vector_type(4))) u16 u16x4;

__device__ __forceinline__ u16 f2bf(float x){
  unsigned u = __float_as_uint(x);
  u = (u + 0x7fffu + ((u >> 16) & 1u)) >> 16;
  return (u16)u;
}
__device__ __forceinline__ float bf2f(u16 h){ return __uint_as_float(((unsigned)h) << 16); }

__device__ __forceinline__ void atomAddF(float* p, float v){
  __hip_atomic_fetch_add(p, v, __ATOMIC_RELAXED, __HIP_MEMORY_SCOPE_AGENT);
}

__device__ __forceinline__ f32x4 mfma_bb(short8 a, short8 b, f32x4 c){
  return __builtin_amdgcn_mfma_f32_16x16x32_bf16(
      __builtin_bit_cast(bf16x8, a), __builtin_bit_cast(bf16x8, b), c, 0, 0, 0);
}

// ---------------- prep: W1,W2 -> transposed bf16 hi/lo ----------------
__global__ __launch_bounds__(256) void k_prep(const float* __restrict__ W1, const float* __restrict__ W2,
                                              u16* __restrict__ w1h, u16* __restrict__ w1l,
                                              u16* __restrict__ w2h, u16* __restrict__ w2l){
  int idx = blockIdx.x * 256 + threadIdx.x;      // 0 .. 131071
  int e = idx & 65535;
  int k = e >> 8, c = e & 255;
  float x = (idx < 65536) ? W1[e] : W2[e];       // W[k][c]
  u16 hi = f2bf(x);
  u16 lo = f2bf(x - bf2f(hi));
  int o = c * 256 + k;                           // Wt[c][k]
  if (idx < 65536){ w1h[o] = hi; w1l[o] = lo; }
  else            { w2h[o] = hi; w2l[o] = lo; }
}

// ---------------- counting sort: hist / scan / scatter ----------------
__global__ __launch_bounds__(256) void k_hist(const int* __restrict__ seg, int* __restrict__ hist){
  int i = blockIdx.x * 256 + threadIdx.x;
  if (i < NA) atomicAdd(&hist[seg[i]], 1);
}

__global__ __launch_bounds__(256) void k_scan(const int* __restrict__ hist, int* __restrict__ cursor){
  __shared__ int ts[256];
  int tid = threadIdx.x;
  int v[8], s = 0;
  #pragma unroll
  for (int j = 0; j < 8; j++){ v[j] = hist[tid * 8 + j]; s += v[j]; }
  ts[tid] = s;
  __syncthreads();
  for (int off = 1; off < 256; off <<= 1){
    int x = (tid >= off) ? ts[tid - off] : 0;
    __syncthreads();
    ts[tid] += x;
    __syncthreads();
  }
  int base = ts[tid] - s;                        // exclusive prefix of thread totals
  #pragma unroll
  for (int j = 0; j < 8; j++){ cursor[tid * 8 + j] = base; base += v[j]; }
}

__global__ __launch_bounds__(256) void k_scatter(const int* __restrict__ seg, int* __restrict__ cursor,
                                                 int* __restrict__ perm){
  int i = blockIdx.x * 256 + threadIdx.x;
  if (i < NA){
    int pos = atomicAdd(&cursor[seg[i]], 1);
    perm[pos] = i;
  }
}

// ---------------- vector branch pass 2: exact (x-mean)^2 scatter ----------------
__global__ __launch_bounds__(256) void k_vec2(const float* __restrict__ vmag, const int* __restrict__ seg,
                                              const float* __restrict__ vsum, const int* __restrict__ hist,
                                              float* __restrict__ vvar){
  int i = blockIdx.x * 256 + threadIdx.x;
  if (i < NA){
    int f = seg[i];
    float c = fmaxf((float)hist[f], 1.0f);
    float d = vmag[i] - vsum[f] / c;
    atomAddF(&vvar[f], d * d);
  }
}

// ---------------- Wv column sums ----------------
__global__ __launch_bounds__(256) void k_wv1(const float* __restrict__ Wv, float* __restrict__ colsum){
  int c = threadIdx.x;
  int r0 = blockIdx.x * 4;
  float s = Wv[(size_t)r0*256 + c] + Wv[(size_t)(r0+1)*256 + c] +
            Wv[(size_t)(r0+2)*256 + c] + Wv[(size_t)(r0+3)*256 + c];
  atomAddF(&colsum[c], s);
}

__global__ __launch_bounds__(256) void k_wv2(const float* __restrict__ colsum, float* __restrict__ scal){
  __shared__ float red[4];
  int tid = threadIdx.x;
  float c = colsum[tid];
  float q = c * c;
  #pragma unroll
  for (int m = 1; m <= 32; m <<= 1) q += __shfl_xor(q, m);
  if ((tid & 63) == 0) red[tid >> 6] = q;
  __syncthreads();
  if (tid == 0) scal[0] = red[0] + red[1] + red[2] + red[3];   // S = ||colsum(Wv)||^2
}

// ---------------- fused scalar MLP GEMM helper (MFMA, bf16 hi/lo split) ----------------
__device__ __forceinline__ void gemm_tile(const u16* Ah, const u16* Al,
                                          const u16* __restrict__ wh, const u16* __restrict__ wl,
                                          int w, int lm, int lk, f32x4 (&acc)[4][4]){
  #pragma unroll
  for (int ks = 0; ks < 8; ks++){
    short8 ah[4], al[4], bh[4], bl[4];
    #pragma unroll
    for (int mi = 0; mi < 4; mi++){
      int row = mi * 16 + lm;
      int boff = (ks * 64 + lk * 16) ^ ((row & 7) << 4);
      ah[mi] = *reinterpret_cast<const short8*>(reinterpret_cast<const char*>(Ah) + row * 512 + boff);
      al[mi] = *reinterpret_cast<const short8*>(reinterpret_cast<const char*>(Al) + row * 512 + boff);
    }
    #pragma unroll
    for (int ni = 0; ni < 4; ni++){
      size_t o = (size_t)(w * 64 + ni * 16 + lm) * HH + ks * 32 + lk * 8;
      bh[ni] = *reinterpret_cast<const short8*>(wh + o);
      bl[ni] = *reinterpret_cast<const short8*>(wl + o);
    }
    #pragma unroll
    for (int mi = 0; mi < 4; mi++){
      #pragma unroll
      for (int ni = 0; ni < 4; ni++){
        acc[mi][ni] = mfma_bb(ah[mi], bh[ni], acc[mi][ni]);
        acc[mi][ni] = mfma_bb(ah[mi], bl[ni], acc[mi][ni]);
        acc[mi][ni] = mfma_bb(al[mi], bh[ni], acc[mi][ni]);
      }
    }
  }
}

// ---------------- mega kernel: vec-role (streaming) + scalar-role (MLP) interleaved ----------------
__global__ __launch_bounds__(256, 2) void k_mega(
    const float* __restrict__ vs, const float* __restrict__ vl,
    const float* __restrict__ ss, const float* __restrict__ sl,
    const int* __restrict__ seg, const int* __restrict__ perm,
    const u16* __restrict__ w1h, const u16* __restrict__ w1l,
    const u16* __restrict__ w2h, const u16* __restrict__ w2l,
    const float* __restrict__ b1, const float* __restrict__ lng,
    const float* __restrict__ lnb, const float* __restrict__ b2,
    float* __restrict__ vmag, float* __restrict__ vsum,
    float* __restrict__ psum, float* __restrict__ psumsq)
{
  __shared__ char smem[65536];          // scalar-role: Ah(32K)|Al(32K), reused as 64K f32 out
  __shared__ float psl[4][64];
  __shared__ float psq[4][64];
  __shared__ float mS[64], rS[64];
  __shared__ int fidv[64], idxv[64];
  __shared__ unsigned long long runmask;

  const int bid = blockIdx.x;
  const int tid = threadIdx.x;
  const int lane = tid & 63;
  const int w = tid >> 6;

  if (bid % 17 != 0){
    // ================= vec role: 4 atoms/block, vmag + segment sums =================
    int vid = bid - bid / 17 - 1;                // 0 .. 24999
    int atom = vid * 4 + w;
    if (atom >= NA) return;
    size_t base = (size_t)atom * (3 * HH) + lane * 4;
    float s[3];
    #pragma unroll
    for (int r = 0; r < 3; r++){
      float4 a = *reinterpret_cast<const float4*>(vs + base + r * HH);
      float4 b = *reinterpret_cast<const float4*>(vl + base + r * HH);
      float c0 = 0.5f*(a.x+b.x), c1 = 0.5f*(a.y+b.y), c2 = 0.5f*(a.z+b.z), c3 = 0.5f*(a.w+b.w);
      s[r] = c0*c0 + c1*c1 + c2*c2 + c3*c3;
    }
    #pragma unroll
    for (int m = 1; m <= 32; m <<= 1){
      s[0] += __shfl_xor(s[0], m);
      s[1] += __shfl_xor(s[1], m);
      s[2] += __shfl_xor(s[2], m);
    }
    if (lane == 0){
      float vm = (sqrtf(s[0]) + sqrtf(s[1]) + sqrtf(s[2])) * (1.0f / 3.0f);
      vmag[atom] = vm;
      atomAddF(&vsum[seg[atom]], vm);
    }
    return;
  }

  // ================= scalar role: fused MLP for 64 sorted atoms =================
  const int sid = bid / 17;                      // 0 .. 1562
  const int lm = lane & 15, lk = lane >> 4;
  const int aBase = sid * 64;

  u16* Ah = (u16*)smem;
  u16* Al = (u16*)(smem + 32768);

  if (tid < 64){
    int g = aBase + tid;
    int ix = (g < NA) ? perm[g] : -1;
    idxv[tid] = ix;
    fidv[tid] = (ix >= 0) ? seg[ix] : 0x7fffffff;   // sentinel for pad rows
  }
  __syncthreads();

  // ---- stage sc = 0.5*(ss+sl) for sorted atoms, split hi/lo into LDS ----
  #pragma unroll
  for (int i = 0; i < 16; i++){
    int fi = i * 256 + tid;             // float4 index
    int row = fi >> 6, c4 = fi & 63;
    int ix = idxv[row];
    float4 a = {0,0,0,0}, b = {0,0,0,0};
    if (ix >= 0){
      a = *reinterpret_cast<const float4*>(ss + (size_t)ix * HH + c4 * 4);
      b = *reinterpret_cast<const float4*>(sl + (size_t)ix * HH + c4 * 4);
    }
    float x0 = 0.5f*(a.x+b.x), x1 = 0.5f*(a.y+b.y), x2 = 0.5f*(a.z+b.z), x3 = 0.5f*(a.w+b.w);
    u16 h0 = f2bf(x0), h1 = f2bf(x1), h2 = f2bf(x2), h3 = f2bf(x3);
    u16x4 hv = {h0, h1, h2, h3};
    u16x4 lv = {f2bf(x0 - bf2f(h0)), f2bf(x1 - bf2f(h1)), f2bf(x2 - bf2f(h2)), f2bf(x3 - bf2f(h3))};
    int boff = (c4 * 8) ^ ((row & 7) << 4);
    *reinterpret_cast<u16x4*>(reinterpret_cast<char*>(Ah) + row * 512 + boff) = hv;
    *reinterpret_cast<u16x4*>(reinterpret_cast<char*>(Al) + row * 512 + boff) = lv;
  }
  __syncthreads();

  // ---- GEMM1: h = sc @ W1 ----
  f32x4 acc[4][4];
  #pragma unroll
  for (int mi = 0; mi < 4; mi++)
    #pragma unroll
    for (int ni = 0; ni < 4; ni++) acc[mi][ni] = (f32x4)0.0f;

  gemm_tile(Ah, Al, w1h, w1l, w, lm, lk, acc);

  #pragma unroll
  for (int ni = 0; ni < 4; ni++){
    float bb = b1[w * 64 + ni * 16 + lm];
    #pragma unroll
    for (int mi = 0; mi < 4; mi++) acc[mi][ni] += bb;
  }

  // ---- LayerNorm stats (cross-wave via LDS partials) ----
  #pragma unroll
  for (int mi = 0; mi < 4; mi++){
    #pragma unroll
    for (int j = 0; j < 4; j++){
      float p = acc[mi][0][j] + acc[mi][1][j] + acc[mi][2][j] + acc[mi][3][j];
      float q = acc[mi][0][j]*acc[mi][0][j] + acc[mi][1][j]*acc[mi][1][j]
              + acc[mi][2][j]*acc[mi][2][j] + acc[mi][3][j]*acc[mi][3][j];
      #pragma unroll
      for (int m = 1; m <= 8; m <<= 1){ p += __shfl_xor(p, m); q += __shfl_xor(q, m); }
      if (lm == 0){ int atom = mi * 16 + lk * 4 + j; psl[w][atom] = p; psq[w][atom] = q; }
    }
  }
  __syncthreads();
  if (tid < 64){
    float s = psl[0][tid] + psl[1][tid] + psl[2][tid] + psl[3][tid];
    float q = psq[0][tid] + psq[1][tid] + psq[2][tid] + psq[3][tid];
    float mean = s * (1.0f / HH);
    float var = q * (1.0f / HH) - mean * mean;
    mS[tid] = mean;
    rS[tid] = rsqrtf(var + 1e-5f);
  }
  __syncthreads();

  // ---- normalize + SiLU + split -> LDS (input of GEMM2) ----
  {
    float gv[4], bv[4];
    #pragma unroll
    for (int ni = 0; ni < 4; ni++){
      int chan = w * 64 + ni * 16 + lm;
      gv[ni] = lng[chan]; bv[ni] = lnb[chan];
    }
    #pragma unroll
    for (int mi = 0; mi < 4; mi++){
      #pragma unroll
      for (int j = 0; j < 4; j++){
        int atom = mi * 16 + lk * 4 + j;
        float mean = mS[atom], rstd = rS[atom];
        #pragma unroll
        for (int ni = 0; ni < 4; ni++){
          float x = (acc[mi][ni][j] - mean) * rstd * gv[ni] + bv[ni];
          float sx = x / (1.0f + __expf(-x));
          u16 hi = f2bf(sx);
          u16 lo = f2bf(sx - bf2f(hi));
          int chan = w * 64 + ni * 16 + lm;
          int boff = (chan * 2) ^ ((atom & 7) << 4);
          *reinterpret_cast<u16*>(reinterpret_cast<char*>(Ah) + atom * 512 + boff) = hi;
          *reinterpret_cast<u16*>(reinterpret_cast<char*>(Al) + atom * 512 + boff) = lo;
        }
      }
    }
  }
  __syncthreads();

  // ---- GEMM2: proj = act @ W2 ----
  #pragma unroll
  for (int mi = 0; mi < 4; mi++)
    #pragma unroll
    for (int ni = 0; ni < 4; ni++) acc[mi][ni] = (f32x4)0.0f;

  gemm_tile(Ah, Al, w2h, w2l, w, lm, lk, acc);

  __syncthreads();                       // all waves done reading Ah/Al

  // ---- write proj (+b2) as swizzled f32 rows into the 64KB LDS buffer ----
  {
    float b2v[4];
    #pragma unroll
    for (int ni = 0; ni < 4; ni++) b2v[ni] = b2[w * 64 + ni * 16 + lm];
    #pragma unroll
    for (int mi = 0; mi < 4; mi++){
      #pragma unroll
      for (int j = 0; j < 4; j++){
        int row = mi * 16 + lk * 4 + j;
        #pragma unroll
        for (int ni = 0; ni < 4; ni++){
          int chan = w * 64 + ni * 16 + lm;
          int boff = (chan * 4) ^ ((row & 7) << 4);
          *reinterpret_cast<float*>(smem + row * 1024 + boff) = acc[mi][ni][j] + b2v[ni];
        }
      }
    }
  }

  // ---- run-segmented reduction over sorted fragment ids ----
  if (tid < 64){
    bool flag = (tid == 0) || (fidv[tid] != fidv[tid - 1]);
    unsigned long long m = __ballot(flag);
    if (tid == 0) runmask = m;
  }
  __syncthreads();                       // orders f32 writes + runmask for all waves

  unsigned long long m = runmask;
  int s = 0;
  while (s < 64){
    unsigned long long rest = (s < 63) ? (m >> (s + 1)) : 0ULL;
    int e = rest ? (s + __ffsll(rest)) : 64;
    int f = fidv[s];
    if (f < FF){
      float s1 = 0.0f, s2 = 0.0f;
      for (int r = s; r < e; r++){
        float x = *reinterpret_cast<const float*>(smem + r * 1024 + ((tid * 4) ^ ((r & 7) << 4)));
        s1 += x; s2 += x * x;
      }
      atomAddF(&psum[(size_t)f * HH + tid], s1);
      #pragma unroll
      for (int mm = 1; mm <= 32; mm <<= 1) s2 += __shfl_xor(s2, mm);
      if (lane == 0) atomAddF(&psumsq[f], s2);
    }
    s = e;
  }
}

// ---------------- per-fragment: group, nrm (bf16 hi/lo), target head, intra/vloss ----------------
__global__ __launch_bounds__(256) void k_group(
    const float* __restrict__ psum, const float* __restrict__ psumsq,
    const int* __restrict__ hist, const float* __restrict__ vvar,
    const float* __restrict__ Wt1, const float* __restrict__ bt1,
    const float* __restrict__ Wt2, const float* __restrict__ bt2,
    float* __restrict__ scal, u16* __restrict__ nh, u16* __restrict__ nl)
{
  __shared__ float g_lds[256];
  __shared__ float red[4];
  __shared__ float sh_norm2, sh_inv;
  int f = blockIdx.x, tid = threadIdx.x;
  int lane = tid & 63, w = tid >> 6;
  float cn = (float)hist[f];
  float safe = fmaxf(cn, 1.0f);
  float g = psum[(size_t)f * HH + tid] / safe;
  g_lds[tid] = g;
  float q = g * g;
  #pragma unroll
  for (int m = 1; m <= 32; m <<= 1) q += __shfl_xor(q, m);
  if (lane == 0) red[w] = q;
  __syncthreads();
  if (tid == 0){
    float n2 = red[0] + red[1] + red[2] + red[3];
    sh_norm2 = n2;
    sh_inv = 1.0f / fmaxf(sqrtf(n2), 1e-12f);
  }
  __syncthreads();
  float nv = g * sh_inv;
  u16 hi = f2bf(nv);
  nh[(size_t)f * HH + tid] = hi;
  nl[(size_t)f * HH + tid] = f2bf(nv - bf2f(hi));

  if (tid < 32){                       // adaptive target head
    float u = bt1[tid];
    for (int k = 0; k < 256; k++) u += g_lds[k] * Wt1[k * 32 + tid];
    u = u / (1.0f + __expf(-u));       // silu
    float tv = u * Wt2[tid];
    #pragma unroll
    for (int m = 1; m <= 16; m <<= 1) tv += __shfl_xor(tv, m);
    if (tid == 0){
      float t = tv + bt2[0];
      t = 1.0f / (1.0f + __expf(-t));
      t = fminf(fmaxf(t, 0.2f), 0.8f);
      atomAddF(&scal[1], t);           // target_sum
    }
  }
  if (tid == 64){
    if (cn >= 2.0f){
      float var = psumsq[f] / safe - sh_norm2;          // sumsq/cnt - ||mu||^2
      atomAddF(&scal[2], sqrtf(var + 1e-8f));           // intra_sum
      atomAddF(&scal[3], 1.0f);                         // nvalid
      float vv = vvar[f] / safe * scal[0];              // * S
      atomAddF(&scal[4], sqrtf(vv + 1e-8f));            // vloss_sum
    }
  }
}

// ---------------- pairwise similarity Huber (MFMA on bf16 hi/lo nrm) ----------------
__global__ __launch_bounds__(256, 1) void k_sim(const u16* __restrict__ nh, const u16* __restrict__ nl,
                                                const float* __restrict__ scal, float* __restrict__ simsum){
  __shared__ float red[4];
  int b = blockIdx.x;
  int bi = 0, rem = b;                          // decode upper-tri 16x16 tile grid (128x128 tiles)
  while (rem >= 16 - bi){ rem -= 16 - bi; bi++; }
  int bj = bi + rem;
  int tid = threadIdx.x, lane = tid & 63, w = tid >> 6;
  int wr = w >> 1, wc = w & 1;
  int lm = lane & 15, lk = lane >> 4;
  int ibase = bi * 128 + wr * 64, jbase = bj * 128 + wc * 64;

  f32x4 acc[4][4];
  #pragma unroll
  for (int mi = 0; mi < 4; mi++)
    #pragma unroll
    for (int ni = 0; ni < 4; ni++) acc[mi][ni] = (f32x4)0.0f;

  #pragma unroll
  for (int ks = 0; ks < 8; ks++){
    short8 ah[4], al[4], bh[4], bl[4];
    #pragma unroll
    for (int mi = 0; mi < 4; mi++){
      size_t o = (size_t)(ibase + mi * 16 + lm) * HH + ks * 32 + lk * 8;
      ah[mi] = *reinterpret_cast<const short8*>(nh + o);
      al[mi] = *reinterpret_cast<const short8*>(nl + o);
    }
    #pragma unroll
    for (int ni = 0; ni < 4; ni++){
      size_t o = (size_t)(jbase + ni * 16 + lm) * HH + ks * 32 + lk * 8;
      bh[ni] = *reinterpret_cast<const short8*>(nh + o);
      bl[ni] = *reinterpret_cast<const short8*>(nl + o);
    }
    #pragma unroll
    for (int mi = 0; mi < 4; mi++)
      #pragma unroll
      for (int ni = 0; ni < 4; ni++){
        acc[mi][ni] = mfma_bb(ah[mi], bh[ni], acc[mi][ni]);
        acc[mi][ni] = mfma_bb(ah[mi], bl[ni], acc[mi][ni]);
        acc[mi][ni] = mfma_bb(al[mi], bh[ni], acc[mi][ni]);
      }
  }

  float target = scal[1] * (1.0f / (float)FF);
  float lsum = 0.0f;
  #pragma unroll
  for (int mi = 0; mi < 4; mi++){
    #pragma unroll
    for (int ni = 0; ni < 4; ni++){
      #pragma unroll
      for (int j = 0; j < 4; j++){
        int gi = ibase + mi * 16 + lk * 4 + j;
        int gj = jbase + ni * 16 + lm;
        if (gj > gi){
          float sim = acc[mi][ni][j];              // TEMP = 1.0
          float d = fabsf(sim - target);
          lsum += (d < 0.1f) ? 0.5f * d * d : 0.1f * (d - 0.05f);
        }
      }
    }
  }
  #pragma unroll
  for (int m = 1; m <= 32; m <<= 1) lsum += __shfl_xor(lsum, m);
  if (lane == 0) red[w] = lsum;
  __syncthreads();
  if (tid == 0) atomAddF(simsum, red[0] + red[1] + red[2] + red[3]);
}

// ---------------- final combine ----------------
__global__ void k_final(const float* __restrict__ scal, float* __restrict__ out){
  float nv = scal[3];
  float intra = (nv > 0.0f) ? scal[2] / fmaxf(nv, 1.0f) : 0.0f;
  float vloss = (nv > 0.0f) ? scal[4] / fmaxf(nv, 1.0f) : 0.0f;
  float gsl = scal[5] * (1.0f / 2096128.0f);     // F*(F-1)/2
  out[0] = 0.05f * (0.3f * intra + 0.7f * gsl + 0.1f * vloss);
}

extern "C" void kernel_launch(void* const* d_in, const int* in_sizes, int n_in,
                              void* d_out, int out_size, void* d_ws, size_t ws_size,
                              hipStream_t stream){
  (void)in_sizes; (void)n_in; (void)out_size; (void)ws_size;
  const float* ss  = (const float*)d_in[0];
  const float* sl  = (const float*)d_in[1];
  const float* vs  = (const float*)d_in[2];
  const float* vl  = (const float*)d_in[3];
  const float* W1  = (const float*)d_in[4];
  const float* b1  = (const float*)d_in[5];
  const float* lng = (const float*)d_in[6];
  const float* lnb = (const float*)d_in[7];
  const float* W2  = (const float*)d_in[8];
  const float* b2  = (const float*)d_in[9];
  const float* Wv  = (const float*)d_in[10];
  const float* Wt1 = (const float*)d_in[11];
  const float* bt1 = (const float*)d_in[12];
  const float* Wt2 = (const float*)d_in[13];
  const float* bt2 = (const float*)d_in[14];
  const int*   seg = (const int*)d_in[15];

  float* ws = (float*)d_ws;
  // ---- zeroed region ----
  float* scal   = ws;                  // [0]=S [1]=target_sum [2]=intra_sum [3]=nvalid [4]=vloss_sum [5]=simsum
  float* colsum = scal + 16;           // 256
  float* vsum   = colsum + 256;        // 2048
  float* vvar   = vsum + FF;           // 2048
  float* psumsq = vvar + FF;           // 2048
  int*   hist   = (int*)(psumsq + FF); // 2048
  float* psum   = (float*)(hist + FF); // FF*HH
  // ---- fully-overwritten region ----
  int*   cursor = (int*)(psum + (size_t)FF * HH);  // 2048
  int*   perm   = cursor + FF;                     // 100000
  float* vmag   = (float*)(perm + NA);             // 100000
  u16*   w1h    = (u16*)(vmag + NA);
  u16*   w1l    = w1h + 65536;
  u16*   w2h    = w1l + 65536;
  u16*   w2l    = w2h + 65536;
  u16*   nh     = w2l + 65536;
  u16*   nl     = nh + (size_t)FF * HH;

  size_t zbytes = (size_t)(16 + 256 + 4 * FF + (size_t)FF * HH) * 4;
  hipMemsetAsync(d_ws, 0, zbytes, stream);

  k_prep   <<<dim3(512),              dim3(256), 0, stream>>>(W1, W2, w1h, w1l, w2h, w2l);
  k_hist   <<<dim3((NA+255)/256),     dim3(256), 0, stream>>>(seg, hist);
  k_scan   <<<dim3(1),                dim3(256), 0, stream>>>(hist, cursor);
  k_scatter<<<dim3((NA+255)/256),     dim3(256), 0, stream>>>(seg, cursor, perm);
  k_wv1    <<<dim3(64),               dim3(256), 0, stream>>>(Wv, colsum);
  k_wv2    <<<dim3(1),                dim3(256), 0, stream>>>(colsum, scal);
  k_mega   <<<dim3(MEGA_BLOCKS),      dim3(256), 0, stream>>>(vs, vl, ss, sl, seg, perm,
                                                              w1h, w1l, w2h, w2l,
                                                              b1, lng, lnb, b2,
                                                              vmag, vsum, psum, psumsq);
  k_vec2   <<<dim3((NA+255)/256),     dim3(256), 0, stream>>>(vmag, seg, vsum, hist, vvar);
  k_group  <<<dim3(FF),               dim3(256), 0, stream>>>(psum, psumsq, hist, vvar,
                                                              Wt1, bt1, Wt2, bt2, scal, nh, nl);
  k_sim    <<<dim3(136),              dim3(256), 0, stream>>>(nh, nl, scal, scal + 5);
  k_final  <<<dim3(1),                dim3(1),   0, stream>>>(scal, (float*)d_out);
}